// Round 3
// baseline (338.316 us; speedup 1.0000x reference)
//
#include <hip/hip_runtime.h>
#include <hip/hip_bf16.h>
#include <math.h>

// Problem constants
#define Bb 2
#define Mm 2048
#define Nn 2048
#define Ff 8
#define Gg 60
#define Kk 32
#define Dd 32
#define Hh 4
#define DHh 8

// ---------------------------------------------------------------------------
// Kernel 1: transpose target (B,D,N,1) -> targetT (B,N,D) for coalesced dots
// ---------------------------------------------------------------------------
__global__ __launch_bounds__(256) void transpose_kernel(
    const float* __restrict__ target, float* __restrict__ tT)
{
    __shared__ float tile[32][33];
    int blk = blockIdx.x;          // 0..127  (B * N/32)
    int b = blk >> 6;
    int n0 = (blk & 63) << 5;
    int t = threadIdx.x;
    int col = t & 31;
    int rowb = t >> 5;             // 0..7
#pragma unroll
    for (int i = 0; i < 4; ++i) {
        int d = rowb + i * 8;
        tile[d][col] = target[(b * 32 + d) * 2048 + n0 + col];
    }
    __syncthreads();
#pragma unroll
    for (int i = 0; i < 4; ++i) {
        int r = rowb + i * 8;      // local n
        tT[(b * 2048 + n0 + r) * 32 + col] = tile[col][r];
    }
}

// ---------------------------------------------------------------------------
// Kernel 2: fused score + top-32 per row m.  One wave (64 threads) per row.
// Each thread owns n = t + 64*j (j<32), scores kept in registers.
// Butterfly argmax x32 with jax.lax.top_k tie-break (min index wins).
// ---------------------------------------------------------------------------
__global__ __launch_bounds__(64) void score_topk_kernel(
    const float* __restrict__ src, const float* __restrict__ tT,
    int* __restrict__ knn)
{
    __shared__ float s[32];
    int blk = blockIdx.x;
    int b = blk >> 11;
    int m = blk & 2047;
    int t = threadIdx.x;
    if (t < 32) s[t] = src[(b * 32 + t) * 2048 + m];
    __syncthreads();
    float sr[32];
#pragma unroll
    for (int i = 0; i < 32; ++i) sr[i] = s[i];

    const float4* tp = (const float4*)(tT + b * 2048 * 32);
    float val[32];
    float bestv = -INFINITY;
    int besti = 0x7FFFFFFF;
#pragma unroll
    for (int j = 0; j < 32; ++j) {
        int n = t + (j << 6);
        const float4* col = tp + n * 8;
        float acc = 0.f;
#pragma unroll
        for (int q = 0; q < 8; ++q) {
            float4 v = col[q];
            acc += v.x * sr[q * 4] + v.y * sr[q * 4 + 1] +
                   v.z * sr[q * 4 + 2] + v.w * sr[q * 4 + 3];
        }
        val[j] = acc;
        if (acc > bestv) { bestv = acc; besti = n; }   // ascending n: '>' keeps min idx
    }

    unsigned mask = 0u;
    int* kout = knn + (b * 2048 + m) * 32;
    for (int k = 0; k < 32; ++k) {
        float v = bestv;
        int i = besti;
#pragma unroll
        for (int off = 32; off > 0; off >>= 1) {
            float ov = __shfl_xor(v, off);
            int oi = __shfl_xor(i, off);
            if (ov > v || (ov == v && oi < i)) { v = ov; i = oi; }
        }
        if (t == 0) kout[k] = i;
        if ((i & 63) == t) {               // owner lane: remove & rescan
            mask |= 1u << (i >> 6);
            bestv = -INFINITY;
            besti = 0x7FFFFFFF;
#pragma unroll
            for (int j = 0; j < 32; ++j) {
                if (!((mask >> j) & 1u) && val[j] > bestv) {
                    bestv = val[j];
                    besti = t + (j << 6);
                }
            }
        }
    }
}

// ---------------------------------------------------------------------------
// Kernel 3: fused gather + QKV + attention + feat_attn + MLP layer 1.
// One block (256 thr) per (b,m). Head h owns channels d with d%4==h.
// ---------------------------------------------------------------------------
__global__ __launch_bounds__(256) void attn_kernel(
    const float* __restrict__ src, const float* __restrict__ featinv,
    const float* __restrict__ tT, const int* __restrict__ knn,
    const float* __restrict__ wq, const float* __restrict__ bq,
    const float* __restrict__ wk, const float* __restrict__ bk,
    const float* __restrict__ wv, const float* __restrict__ bv,
    const float* __restrict__ wm, const float* __restrict__ bm,
    const float* __restrict__ w1, const float* __restrict__ b1,
    float* __restrict__ fat, float* __restrict__ h1out)
{
    __shared__ float kf[32][33], kk[32][33], vv[32][33];
    __shared__ float wks[1024], wvs[1024];       // transposed: [i*32+o]
    __shared__ float s[32], qv[32], xv[32];
    __shared__ float scs[4][32], prob[4][32];
    __shared__ float cat[96];
    __shared__ int idx[32];

    int blk = blockIdx.x;
    int b = blk >> 11;
    int m = blk & 2047;
    int t = threadIdx.x;
    int d = t & 31, kn0 = t >> 5;

    if (t < 32) {
        s[t] = src[(b * 32 + t) * 2048 + m];
        idx[t] = knn[(b * 2048 + m) * 32 + t];
    }
#pragma unroll
    for (int r = 0; r < 4; ++r) {
        int w = t + 256 * r;
        wks[w] = wk[(w & 31) * 32 + (w >> 5)];   // wks[i*32+o] = wk[o][i]
        wvs[w] = wv[(w & 31) * 32 + (w >> 5)];
    }
    __syncthreads();

    // gather 32 neighbor features (coalesced 128B per neighbor)
#pragma unroll
    for (int i = 0; i < 4; ++i) {
        int kn = kn0 + i * 8;
        kf[kn][d] = tT[(b * 2048 + idx[kn]) * 32 + d];
    }
    if (t < 32) {
        float acc = bq[t];
#pragma unroll
        for (int i = 0; i < 32; ++i) acc += wq[t * 32 + i] * s[i];
        qv[t] = acc;
    }
    __syncthreads();

    // K,V projections: thread (o=d, kn = kn0+8i)
#pragma unroll
    for (int i = 0; i < 4; ++i) {
        int kn = kn0 + i * 8;
        float ak = bk[d], av = bv[d];
#pragma unroll
        for (int j = 0; j < 32; ++j) {
            float f = kf[kn][j];
            ak += wks[j * 32 + d] * f;
            av += wvs[j * 32 + d] * f;
        }
        kk[kn][d] = ak;
        vv[kn][d] = av;
    }
    __syncthreads();

    // attention scores: head h uses channels dh*4+h
    if (t < 128) {
        int kn = t >> 2, h = t & 3;
        float acc = 0.f;
#pragma unroll
        for (int dh = 0; dh < 8; ++dh) acc += qv[dh * 4 + h] * kk[kn][dh * 4 + h];
        scs[h][kn] = acc * 0.35355339059327373f;  // 1/sqrt(8)
    }
    __syncthreads();
    if (t < 4) {
        float mx = -INFINITY;
        for (int kn = 0; kn < 32; ++kn) mx = fmaxf(mx, scs[t][kn]);
        float sum = 0.f;
        for (int kn = 0; kn < 32; ++kn) {
            float e = expf(scs[t][kn] - mx);
            prob[t][kn] = e;
            sum += e;
        }
        float inv = 1.f / sum;
        for (int kn = 0; kn < 32; ++kn) prob[t][kn] *= inv;
    }
    __syncthreads();
    if (t < 32) {
        int h = t & 3;
        float acc = 0.f;
#pragma unroll
        for (int kn = 0; kn < 32; ++kn) acc += prob[h][kn] * vv[kn][t];
        xv[t] = acc;
    }
    __syncthreads();
    if (t < 32) {
        float acc = bm[t];
#pragma unroll
        for (int i = 0; i < 32; ++i) acc += wm[t * 32 + i] * xv[i];
        fat[(b * 32 + t) * 2048 + m] = acc;
        cat[t] = featinv[(b * 32 + t) * 2048 + m];
        cat[32 + t] = s[t];
        cat[64 + t] = acc;
    }
    __syncthreads();
    // MLP layer 1 (96 -> 64); instance-norm stats need global pass -> store
    if (t < 64) {
        float acc = b1[t];
#pragma unroll
        for (int i = 0; i < 96; ++i) acc += w1[t * 96 + i] * cat[i];
        h1out[(b * 64 + t) * 2048 + m] = acc;
    }
}

// ---------------------------------------------------------------------------
// Kernel 4: instance-norm stats per (b, channel) over M
// ---------------------------------------------------------------------------
__global__ __launch_bounds__(256) void stats_kernel(
    const float* __restrict__ h1, float* __restrict__ mu, float* __restrict__ rstd)
{
    __shared__ float rs[256], rq[256];
    int bc = blockIdx.x;
    int t = threadIdx.x;
    const float* row = h1 + bc * 2048;
    float sum = 0.f, sq = 0.f;
#pragma unroll
    for (int r = 0; r < 8; ++r) {
        float v = row[t + 256 * r];
        sum += v;
        sq += v * v;
    }
    rs[t] = sum; rq[t] = sq;
    __syncthreads();
    for (int off = 128; off > 0; off >>= 1) {
        if (t < off) { rs[t] += rs[t + off]; rq[t] += rq[t + off]; }
        __syncthreads();
    }
    if (t == 0) {
        float m_ = rs[0] * (1.f / 2048.f);
        float var = rq[0] * (1.f / 2048.f) - m_ * m_;
        mu[bc] = m_;
        rstd[bc] = rsqrtf(var + 1e-5f);
    }
}

// ---------------------------------------------------------------------------
// Kernel 5: norm + ReLU + (w2 @ h + wres @ cat) epilogue -> feat_out
// One block handles 8 m values; thread = (m-sub g, out channel o).
// ---------------------------------------------------------------------------
__global__ __launch_bounds__(256) void final_kernel(
    const float* __restrict__ src, const float* __restrict__ featinv,
    const float* __restrict__ fat, const float* __restrict__ h1,
    const float* __restrict__ mu, const float* __restrict__ rstd,
    const float* __restrict__ w2, const float* __restrict__ b2,
    const float* __restrict__ wres, const float* __restrict__ bres,
    float* __restrict__ out)
{
    __shared__ float hbuf[64][8];
    __shared__ float catbuf[96][8];
    __shared__ float w2s[2048];    // [c*32+o]
    __shared__ float wress[3072];  // [i*32+o]
    int blk = blockIdx.x;
    int b = blk >> 8;
    int m0 = (blk & 255) << 3;
    int t = threadIdx.x;
#pragma unroll
    for (int r = 0; r < 8; ++r) {
        int w = t + 256 * r;
        w2s[w] = w2[(w & 31) * 64 + (w >> 5)];
    }
#pragma unroll
    for (int r = 0; r < 12; ++r) {
        int w = t + 256 * r;
        wress[w] = wres[(w & 31) * 96 + (w >> 5)];
    }
#pragma unroll
    for (int r = 0; r < 2; ++r) {
        int i = t + 256 * r;
        int c = i >> 3, mm = i & 7;
        int bc = b * 64 + c;
        float v = h1[(b * 64 + c) * 2048 + m0 + mm];
        v = (v - mu[bc]) * rstd[bc];
        hbuf[c][mm] = fmaxf(v, 0.f);
    }
#pragma unroll
    for (int r = 0; r < 3; ++r) {
        int i = t + 256 * r;
        int c = i >> 3, mm = i & 7;
        float v;
        if (c < 32)      v = featinv[(b * 32 + c) * 2048 + m0 + mm];
        else if (c < 64) v = src[(b * 32 + (c - 32)) * 2048 + m0 + mm];
        else             v = fat[(b * 32 + (c - 64)) * 2048 + m0 + mm];
        catbuf[c][mm] = v;
    }
    __syncthreads();
    int o = t & 31, g = t >> 5;
    float acc = b2[o] + bres[o];
#pragma unroll
    for (int c = 0; c < 64; ++c) acc += w2s[c * 32 + o] * hbuf[c][g];
#pragma unroll
    for (int i = 0; i < 96; ++i) acc += wress[i * 32 + o] * catbuf[i][g];
    out[(b * 32 + o) * 2048 + m0 + g] = acc;
}

// ---------------------------------------------------------------------------
// Kernel 6: R_indicator. One block per (b,m).
// R[h2] = sum_{f,g} source_eqv[b,f,m,perms[g*60+h2]] * target_eqv[b,f,nn,g]
// ---------------------------------------------------------------------------
__global__ __launch_bounds__(256) void r_kernel(
    const float* __restrict__ source_eqv, const float* __restrict__ target_eqv,
    const int* __restrict__ perms, const int* __restrict__ knn,
    float* __restrict__ out)
{
    __shared__ float tk[8][60];
    __shared__ float se[8][60];
    __shared__ int pl[3600];
    __shared__ float part[4][60];
    int blk = blockIdx.x;
    int b = blk >> 11;
    int m = blk & 2047;
    int t = threadIdx.x;
    int nn = knn[(b * 2048 + m) * 32];   // top-1 index
#pragma unroll
    for (int r = 0; r < 2; ++r) {
        int i = t + 256 * r;
        if (i < 480) {
            int f = i / 60, g = i - f * 60;
            tk[f][g] = target_eqv[((b * 8 + f) * 2048 + nn) * 60 + g];
            se[f][g] = source_eqv[((b * 8 + f) * 2048 + m) * 60 + g];
        }
    }
#pragma unroll
    for (int r = 0; r < 15; ++r) {
        int i = t + 256 * r;
        if (i < 3600) pl[i] = perms[i];
    }
    __syncthreads();
    if (t < 240) {
        int h2 = t % 60, quarter = t / 60;
        float acc = 0.f;
        for (int g = quarter * 15; g < quarter * 15 + 15; ++g) {
            int p = pl[g * 60 + h2];
#pragma unroll
            for (int f = 0; f < 8; ++f) acc += se[f][p] * tk[f][g];
        }
        part[quarter][h2] = acc;
    }
    __syncthreads();
    if (t < 60)
        out[(b * 60 + t) * 2048 + m] =
            part[0][t] + part[1][t] + part[2][t] + part[3][t];
}

// ---------------------------------------------------------------------------
extern "C" void kernel_launch(void* const* d_in, const int* in_sizes, int n_in,
                              void* d_out, int out_size, void* d_ws, size_t ws_size,
                              hipStream_t stream)
{
    const float* source     = (const float*)d_in[0];
    const float* target     = (const float*)d_in[1];
    const float* source_eqv = (const float*)d_in[2];
    const float* target_eqv = (const float*)d_in[3];
    const float* featinv    = (const float*)d_in[4];
    const int*   perms      = (const int*)d_in[5];
    const float* wq = (const float*)d_in[6];   const float* bq = (const float*)d_in[7];
    const float* wk = (const float*)d_in[8];   const float* bk = (const float*)d_in[9];
    const float* wv = (const float*)d_in[10];  const float* bv = (const float*)d_in[11];
    const float* wm = (const float*)d_in[12];  const float* bm = (const float*)d_in[13];
    const float* w1 = (const float*)d_in[14];  const float* b1 = (const float*)d_in[15];
    const float* w2 = (const float*)d_in[16];  const float* b2 = (const float*)d_in[17];
    const float* wres = (const float*)d_in[18]; const float* bres = (const float*)d_in[19];

    float* ws   = (float*)d_ws;
    float* tT   = ws;                       // B*N*32      = 131072 f
    int*   knn  = (int*)(ws + 131072);      // B*M*32      = 131072 i
    float* fat  = ws + 262144;              // B*32*M      = 131072 f
    float* h1   = ws + 393216;              // B*64*M      = 262144 f
    float* mu   = ws + 655360;              // 128 f
    float* rstd = ws + 655488;              // 128 f

    float* feat_out = (float*)d_out;
    float* r_out    = feat_out + Bb * Dd * Mm;   // 131072

    transpose_kernel<<<128, 256, 0, stream>>>(target, tT);
    score_topk_kernel<<<Bb * Mm, 64, 0, stream>>>(source, tT, knn);
    attn_kernel<<<Bb * Mm, 256, 0, stream>>>(source, featinv, tT, knn,
                                             wq, bq, wk, bk, wv, bv, wm, bm,
                                             w1, b1, fat, h1);
    stats_kernel<<<Bb * 64, 256, 0, stream>>>(h1, mu, rstd);
    final_kernel<<<Bb * Mm / 8, 256, 0, stream>>>(source, featinv, fat, h1,
                                                  mu, rstd, w2, b2, wres, bres,
                                                  feat_out);
    r_kernel<<<Bb * Mm, 256, 0, stream>>>(source_eqv, target_eqv, perms, knn, r_out);
}